// Round 2
// baseline (38.851 us; speedup 1.0000x reference)
//
#include <hip/hip_runtime.h>

constexpr int B_DIM    = 256;
constexpr int S_DIM    = 16384;
constexpr int NTHREADS = 1024;
constexpr int NWAVES   = NTHREADS / 64;      // 16
constexpr int CHUNK    = S_DIM / NTHREADS;   // 16 elements per thread
constexpr float DECAY   = 0.95f;             // GAMMA * LAM
constexpr float CLIP_LO = 0.8f;
constexpr float CLIP_HI = 1.2f;

__host__ __device__ constexpr float fpow(float x, int n) {
    float r = 1.0f;
    for (int i = 0; i < n; ++i) r *= x;
    return r;
}

__global__ __launch_bounds__(NTHREADS) void ppo_fused(
    const float* __restrict__ rewards,
    const float* __restrict__ values,
    const float* __restrict__ nlp,
    const float* __restrict__ olp,
    const float* __restrict__ nval,
    const int*   __restrict__ amask,
    float* __restrict__ out)
{
    const int b    = blockIdx.x;
    const int t    = threadIdx.x;
    const int lane = t & 63;
    const int wv   = t >> 6;
    const size_t base = (size_t)b * S_DIM + (size_t)t * CHUNK;

    // per-chunk multiplier A = DECAY^CHUNK and its powers (compile-time)
    constexpr float A1  = fpow(DECAY, CHUNK);
    constexpr float A2  = A1  * A1;
    constexpr float A4  = A2  * A2;
    constexpr float A8  = A4  * A4;
    constexpr float A16 = A8  * A8;
    constexpr float A32 = A16 * A16;
    constexpr float A64 = A32 * A32;

    // ---- pass 1: load rewards+values, compute deltas, chunk aggregate ----
    float r[CHUNK];   // rewards -> deltas -> advantages (in place)
    float v[CHUNK];   // values kept for returns
    {
        const float4* r4 = reinterpret_cast<const float4*>(rewards + base);
        const float4* v4 = reinterpret_cast<const float4*>(values  + base);
        #pragma unroll
        for (int q = 0; q < CHUNK / 4; ++q) {
            float4 rr = r4[q];
            float4 vv = v4[q];
            r[4*q+0] = rr.x; r[4*q+1] = rr.y; r[4*q+2] = rr.z; r[4*q+3] = rr.w;
            v[4*q+0] = vv.x; v[4*q+1] = vv.y; v[4*q+2] = vv.z; v[4*q+3] = vv.w;
        }
    }
    // next value for the last element of this chunk: V_S := 0 bootstrap for
    // the row's final thread, otherwise first value of the next chunk.
    float vnext = 0.0f;
    if (t != NTHREADS - 1) vnext = values[base + CHUNK];

    // deltas (GAMMA == 1): peel the last iteration -> no v[CHUNK] access
    #pragma unroll
    for (int k = 0; k < CHUNK - 1; ++k) r[k] = r[k] + v[k + 1] - v[k];
    r[CHUNK - 1] = r[CHUNK - 1] + vnext - v[CHUNK - 1];

    // chunk aggregate with zero incoming gae: B_t = sum_k DECAY^k * d_k
    float agg = 0.0f;
    #pragma unroll
    for (int k = CHUNK - 1; k >= 0; --k) agg = fmaf(DECAY, agg, r[k]);

    // ---- inclusive wave suffix scan: s_l = sum_{j>=l} A1^(j-l) * B_j ----
    // all shuffle reads are index-clamped to a valid lane; out-of-range
    // contributions are explicitly zeroed.
    float s = agg;
    {
        float o;
        o = __shfl(s, min(lane + 1, 63));  s = fmaf(A1,  (lane < 63) ? o : 0.0f, s);
        o = __shfl(s, min(lane + 2, 63));  s = fmaf(A2,  (lane < 62) ? o : 0.0f, s);
        o = __shfl(s, min(lane + 4, 63));  s = fmaf(A4,  (lane < 60) ? o : 0.0f, s);
        o = __shfl(s, min(lane + 8, 63));  s = fmaf(A8,  (lane < 56) ? o : 0.0f, s);
        o = __shfl(s, min(lane + 16, 63)); s = fmaf(A16, (lane < 48) ? o : 0.0f, s);
        o = __shfl(s, min(lane + 32, 63)); s = fmaf(A32, (lane < 32) ? o : 0.0f, s);
    }

    // ---- inter-wave combine: redundant per-thread (no serial thread-0 pass)
    __shared__ float wagg[NWAVES];
    if (lane == 0) wagg[wv] = s;      // wave aggregate = inclusive scan at lane 0
    __syncthreads();

    // gw = incoming gae for this wave = sum_{w' > wv} A64^(w'-wv-1) * wagg[w']
    float gw = 0.0f;
    #pragma unroll
    for (int w = NWAVES - 1; w >= 1; --w) {
        if (w > wv) gw = fmaf(A64, gw, wagg[w]);   // wave-uniform predicate
    }

    // pw = A1^(64 - lane)
    float pw = 1.0f;
    {
        const int e = 64 - lane;   // 1..64
        if (e & 1)  pw *= A1;
        if (e & 2)  pw *= A2;
        if (e & 4)  pw *= A4;
        if (e & 8)  pw *= A8;
        if (e & 16) pw *= A16;
        if (e & 32) pw *= A32;
        if (e & 64) pw *= A64;
    }
    const float S_incl = fmaf(pw, gw, s);                    // inclusive incl. later waves
    const float Snext  = __shfl(S_incl, min(lane + 1, 63));  // valid-lane read
    const float gin    = (lane == 63) ? gw : Snext;          // exclusive incoming gae

    // ---- pass 2: replay recurrence with correct incoming gae ----
    float g = gin;
    #pragma unroll
    for (int k = CHUNK - 1; k >= 0; --k) { g = fmaf(DECAY, g, r[k]); r[k] = g; }

    // ---- fused PPO + value loss (f64 accumulation) ----
    const float4* a4 = reinterpret_cast<const float4*>(nlp   + base);
    const float4* o4 = reinterpret_cast<const float4*>(olp   + base);
    const float4* n4 = reinterpret_cast<const float4*>(nval  + base);
    const int4*   m4 = reinterpret_cast<const int4*>  (amask + base);

    double sp = 0.0, sv = 0.0;
    float  sm = 0.0f;   // exact: sums of 0/1 integers stay exact in f32 here
    #pragma unroll
    for (int q = 0; q < CHUNK / 4; ++q) {
        float4 a = a4[q];
        float4 o = o4[q];
        float4 n = n4[q];
        int4   m = m4[q];
        float ax[4] = {a.x, a.y, a.z, a.w};
        float ox[4] = {o.x, o.y, o.z, o.w};
        float nx[4] = {n.x, n.y, n.z, n.w};
        int   mx[4] = {m.x, m.y, m.z, m.w};
        #pragma unroll
        for (int j = 0; j < 4; ++j) {
            const int k = 4 * q + j;
            const float adv   = r[k];
            const float ratio = expf(ax[j] - ox[j]);
            const float s1    = ratio * adv;
            const float s2    = fminf(fmaxf(ratio, CLIP_LO), CLIP_HI) * adv;
            const float pl    = -fminf(s1, s2);
            const float mm    = (float)mx[j];
            sp += (double)(pl * mm);
            const float vd = nx[j] - (adv + v[k]);
            sv += (double)(vd * vd) * (double)mm;
            sm += mm;
        }
    }

    // ---- block reduction of (sp, sv, sm) ----
    #pragma unroll
    for (int off = 32; off > 0; off >>= 1) {
        sp += __shfl_down(sp, off);   // lane-0 chain reads are all in-range
        sv += __shfl_down(sv, off);
        sm += __shfl_down(sm, off);
    }
    __shared__ double redp[NWAVES];
    __shared__ double redv[NWAVES];
    __shared__ float  redm[NWAVES];
    if (lane == 0) { redp[wv] = sp; redv[wv] = sv; redm[wv] = sm; }
    __syncthreads();
    if (t == 0) {
        double P = 0.0, V = 0.0;
        float  M = 0.0f;
        #pragma unroll
        for (int w = 0; w < NWAVES; ++w) { P += redp[w]; V += redv[w]; M += redm[w]; }
        const double Md = fmax((double)M, 1e-8);
        out[b]         = (float)(P / Md);   // p_loss
        out[B_DIM + b] = (float)(V / Md);   // v_loss
    }
}

extern "C" void kernel_launch(void* const* d_in, const int* in_sizes, int n_in,
                              void* d_out, int out_size, void* d_ws, size_t ws_size,
                              hipStream_t stream) {
    const float* rewards = (const float*)d_in[0];
    const float* values  = (const float*)d_in[1];
    const float* nlp     = (const float*)d_in[2];
    const float* olp     = (const float*)d_in[3];
    const float* nval    = (const float*)d_in[4];
    const int*   amask   = (const int*)  d_in[5];
    float* out = (float*)d_out;

    ppo_fused<<<B_DIM, NTHREADS, 0, stream>>>(rewards, values, nlp, olp, nval, amask, out);
}

// Round 3
// 24.753 us; speedup vs baseline: 1.5696x; 1.5696x over previous
//
#include <hip/hip_runtime.h>

constexpr int B_DIM  = 256;
constexpr int S_DIM  = 16384;
constexpr int SEG    = 1024;          // elements per wave segment
constexpr int NSEG   = S_DIM / SEG;   // 16 segments per row
constexpr int HALO   = 256;           // decay horizon: 0.95^256 ~ 2e-6
constexpr float DECAY   = 0.95f;      // GAMMA * LAM
constexpr float CLIP_LO = 0.8f;
constexpr float CLIP_HI = 1.2f;

__host__ __device__ constexpr float fpow(float x, int n) {
    float r = 1.0f;
    for (int i = 0; i < n; ++i) r *= x;
    return r;
}

// DECAY^(4e) for e in [0,63] via 6 bit-selected multiplies
__device__ __forceinline__ float dpow4(int e) {
    float p = 1.0f;
    if (e & 1)  p *= fpow(DECAY, 4);
    if (e & 2)  p *= fpow(DECAY, 8);
    if (e & 4)  p *= fpow(DECAY, 16);
    if (e & 8)  p *= fpow(DECAY, 32);
    if (e & 16) p *= fpow(DECAY, 64);
    if (e & 32) p *= fpow(DECAY, 128);
    return p;
}

// K1: each wave independently processes one 1024-element segment (+256 halo).
// No __syncthreads, no LDS staging, fully coalesced float4 loads.
__global__ __launch_bounds__(256) void ppo_seg(
    const float* __restrict__ rewards,
    const float* __restrict__ values,
    const float* __restrict__ nlp,
    const float* __restrict__ olp,
    const float* __restrict__ nval,
    const int*   __restrict__ amask,
    double* __restrict__ part)
{
    const int l   = threadIdx.x & 63;
    const int wid = (blockIdx.x << 2) | (threadIdx.x >> 6);  // global wave id
    const int row = wid >> 4;    // 0..255
    const int seg = wid & 15;    // 0..15
    const size_t base = (size_t)row * S_DIM + (size_t)seg * SEG;
    const size_t i4   = base + 4 * (size_t)l;   // lane's first element

    // ---- coalesced main loads: 4 blocks of 256; lane l holds elems 4l..4l+3
    float4 r4[4], v4[4];
    #pragma unroll
    for (int q = 0; q < 4; ++q) {
        r4[q] = *reinterpret_cast<const float4*>(rewards + i4 + 256 * q);
        v4[q] = *reinterpret_cast<const float4*>(values  + i4 + 256 * q);
    }

    // ---- halo: estimate incoming GAE at segment end (wave-uniform branch)
    float G = 0.0f;        // g at position base+SEG
    float v_end = 0.0f;    // values[base+SEG] (bootstrap 0 for last segment)
    if (seg < NSEG - 1) {
        float4 rh = *reinterpret_cast<const float4*>(rewards + i4 + SEG);
        float4 vh = *reinterpret_cast<const float4*>(values  + i4 + SEG);
        float vhe = values[base + SEG + HALO];   // uniform broadcast load
        float vn = __shfl(vh.x, (l + 1) & 63);
        if (l == 63) vn = vhe;
        const float d0 = rh.x + vh.y - vh.x;
        const float d1 = rh.y + vh.z - vh.y;
        const float d2 = rh.z + vh.w - vh.z;
        const float d3 = rh.w + vn   - vh.w;
        const float c  = fmaf(DECAY, fmaf(DECAY, fmaf(DECAY, d3, d2), d1), d0);
        float u = dpow4(l) * c;          // weight DECAY^(4l)
        #pragma unroll
        for (int m = 1; m < 64; m <<= 1) u += __shfl_xor(u, m);
        G = u;
        v_end = __shfl(vh.x, 0);
    }

    // ---- deltas (GAMMA == 1): d_p = r_p + v_{p+1} - v_p
    const float h1 = __shfl(v4[1].x, 0);
    const float h2 = __shfl(v4[2].x, 0);
    const float h3 = __shfl(v4[3].x, 0);
    const float nx[4] = {h1, h2, h3, v_end};  // next-block head (lane 63 only)

    float d[16];
    #pragma unroll
    for (int q = 0; q < 4; ++q) {
        float vn = __shfl(v4[q].x, (l + 1) & 63);
        if (l == 63) vn = nx[q];
        d[4*q+0] = r4[q].x + v4[q].y - v4[q].x;
        d[4*q+1] = r4[q].y + v4[q].z - v4[q].y;
        d[4*q+2] = r4[q].z + v4[q].w - v4[q].z;
        d[4*q+3] = r4[q].w + vn      - v4[q].w;
    }

    // ---- per-lane chunk aggregates, then 4 parallel cross-lane suffix scans
    float s[4];
    #pragma unroll
    for (int q = 0; q < 4; ++q)
        s[q] = fmaf(DECAY, fmaf(DECAY, fmaf(DECAY, d[4*q+3], d[4*q+2]), d[4*q+1]), d[4*q+0]);

    #pragma unroll
    for (int st = 1; st < 64; st <<= 1) {
        const float f = fpow(DECAY, 4 * st);   // constant-folded
        #pragma unroll
        for (int q = 0; q < 4; ++q) {
            float o = __shfl(s[q], min(l + st, 63));    // valid-lane read
            s[q] = (l < 64 - st) ? fmaf(f, o, s[q]) : s[q];
        }
    }

    // ---- combine across the 4 blocks (scalar, wave-uniform)
    constexpr float A256 = fpow(DECAY, 256);
    const float W1 = __shfl(s[1], 0);
    const float W2 = __shfl(s[2], 0);
    const float W3 = __shfl(s[3], 0);
    const float g3 = G;                      // g at offset 1024
    const float g2 = fmaf(A256, g3, W3);     // g at offset 768
    const float g1 = fmaf(A256, g2, W2);     // g at offset 512
    const float g0 = fmaf(A256, g1, W1);     // g at offset 256
    const float gq[4] = {g0, g1, g2, g3};

    // ---- replay recurrence per block with exact incoming gae
    const float pw = dpow4(63 - l);          // DECAY^(4(63-l))
    #pragma unroll
    for (int q = 0; q < 4; ++q) {
        const float sn  = __shfl(s[q], (l + 1) & 63);
        const float gin = (l < 63) ? fmaf(pw, gq[q], sn) : gq[q];
        float g = gin;
        g = fmaf(DECAY, g, d[4*q+3]); d[4*q+3] = g;   // d[] becomes advantages
        g = fmaf(DECAY, g, d[4*q+2]); d[4*q+2] = g;
        g = fmaf(DECAY, g, d[4*q+1]); d[4*q+1] = g;
        g = fmaf(DECAY, g, d[4*q+0]); d[4*q+0] = g;
    }

    // ---- fused PPO + value loss (f64 accumulation)
    double sp = 0.0, sv = 0.0;
    float  sm = 0.0f;
    #pragma unroll
    for (int q = 0; q < 4; ++q) {
        const float4 a = *reinterpret_cast<const float4*>(nlp   + i4 + 256 * q);
        const float4 o = *reinterpret_cast<const float4*>(olp   + i4 + 256 * q);
        const float4 n = *reinterpret_cast<const float4*>(nval  + i4 + 256 * q);
        const int4   m = *reinterpret_cast<const int4*>  (amask + i4 + 256 * q);
        const float av[4] = {a.x, a.y, a.z, a.w};
        const float ov[4] = {o.x, o.y, o.z, o.w};
        const float nv[4] = {n.x, n.y, n.z, n.w};
        const int   mv[4] = {m.x, m.y, m.z, m.w};
        const float vv[4] = {v4[q].x, v4[q].y, v4[q].z, v4[q].w};
        #pragma unroll
        for (int j = 0; j < 4; ++j) {
            const float adv   = d[4*q+j];
            const float ratio = __expf(av[j] - ov[j]);
            const float s1    = ratio * adv;
            const float s2    = fminf(fmaxf(ratio, CLIP_LO), CLIP_HI) * adv;
            const float pl    = -fminf(s1, s2);
            const float mm    = (float)mv[j];
            sp += (double)(pl * mm);
            const float vd = nv[j] - (adv + vv[j]);
            sv += (double)(vd * vd) * (double)mm;
            sm += mm;
        }
    }

    // ---- wave butterfly reduction, one partial per segment
    #pragma unroll
    for (int m = 1; m < 64; m <<= 1) {
        sp += __shfl_xor(sp, m);
        sv += __shfl_xor(sv, m);
        sm += __shfl_xor(sm, m);
    }
    if (l == 0) {
        double* p = part + (size_t)wid * 3;
        p[0] = sp; p[1] = sv; p[2] = (double)sm;
    }
}

// K2: reduce 16 segment partials per row, write [2, 256]
__global__ __launch_bounds__(256) void ppo_final(
    const double* __restrict__ part, float* __restrict__ out)
{
    const int b = threadIdx.x;   // 0..255, single block
    double P = 0.0, V = 0.0, M = 0.0;
    #pragma unroll
    for (int s2 = 0; s2 < NSEG; ++s2) {
        const double* p = part + ((size_t)b * NSEG + s2) * 3;
        P += p[0]; V += p[1]; M += p[2];
    }
    const double Md = fmax(M, 1e-8);
    out[b]         = (float)(P / Md);
    out[B_DIM + b] = (float)(V / Md);
}

extern "C" void kernel_launch(void* const* d_in, const int* in_sizes, int n_in,
                              void* d_out, int out_size, void* d_ws, size_t ws_size,
                              hipStream_t stream) {
    const float* rewards = (const float*)d_in[0];
    const float* values  = (const float*)d_in[1];
    const float* nlp     = (const float*)d_in[2];
    const float* olp     = (const float*)d_in[3];
    const float* nval    = (const float*)d_in[4];
    const int*   amask   = (const int*)  d_in[5];
    float* out = (float*)d_out;
    double* part = (double*)d_ws;   // 256*16*3 doubles = 96 KiB

    ppo_seg<<<B_DIM * NSEG / 4, 256, 0, stream>>>(rewards, values, nlp, olp, nval, amask, part);
    ppo_final<<<1, 256, 0, stream>>>(part, out);
}